// Round 15
// baseline (2717.595 us; speedup 1.0000x reference)
//
#include <hip/hip_runtime.h>

#define B 8
#define N 16384
#define NPOINT 1024
#define NSAMPLE 32
#define CDIM 128
#define NW 4                  // workgroups per batch (fps)
#define PPW (N / NW)          // 4096 points per WG
#define PPT (PPW / 1024)      // 4 points per thread

// d_out layout (floats), reference return order:
// new_xyz [B,NPOINT,3], new_points [B,NPOINT,NSAMPLE,CDIM], idx [B,NPOINT,NSAMPLE], grouped_xyz [B,NPOINT,NSAMPLE,3]
#define OFF_NEWXYZ 0
#define OFF_NEWPTS (B * NPOINT * 3)                           // 24576
#define OFF_IDX    (OFF_NEWPTS + B * NPOINT * NSAMPLE * CDIM) // 33579008
#define OFF_GXYZ   (OFF_IDX + B * NPOINT * NSAMPLE)           // 33841152

typedef float f32x2 __attribute__((ext_vector_type(2)));

// gfx950 packed f32: only v_pk_add_f32 / v_pk_mul_f32 / v_pk_fma_f32 exist
// (NO pk_min/max — r13). Per-half IEEE identical to scalar ops.
static __device__ __forceinline__ f32x2 pk_sub(f32x2 a, f32x2 b) {
    f32x2 d;
    asm("v_pk_add_f32 %0, %1, %2 neg_lo:[0,1] neg_hi:[0,1]" : "=v"(d) : "v"(a), "v"(b));
    return d;
}
static __device__ __forceinline__ f32x2 pk_mul(f32x2 a, f32x2 b) {
    f32x2 d;
    asm("v_pk_mul_f32 %0, %1, %2" : "=v"(d) : "v"(a), "v"(b));
    return d;
}

// DPP max step: m = max(m, lane-shifted m); invalid lanes keep old -> identity.
template <int CTRL>
__device__ __forceinline__ float maxdpp(float m) {
    const int t = __builtin_amdgcn_update_dpp(__float_as_int(m), __float_as_int(m),
                                              CTRL, 0xf, 0xf, false);
    return fmaxf(m, __int_as_float(t));
}

// ---------------- FPS: NW=4 workgroups per batch (32 CUs busy) ----------------
// Exact f32 left-assoc ops; argmax tie-break = first index, carried exactly by
// u64-min keys: key = (~bits(d) << 14) | n  (d>=0 -> ~bits monotone decreasing).
// Per-thread state: 4 pts = 8 xy + 4 z + 4 d = 24 VGPRs -> below the 52 the
// allocator grants -> NO spill (r4/r5/r12/r14: 64-float state always spilled).
// Cross-WG per-step argmax via mailboxes in d_ws:
//   owner: store key (relaxed) then step-counter s+1 (release);
//   readers: lanes 0..NW-1 spin acquire-load counters == s+1 (exact equality:
//   stale values from a prior graph replay are always 1023 or poison, never
//   matching the live sequence 1,2,3,... because skew between WGs is <=1 step),
//   then min-combine the NW keys in-wave. No RMW contention, no resets.
__global__ __launch_bounds__(1024) void fps_kernel(const float* __restrict__ xyz,
                                                   float* out,
                                                   unsigned long long* __restrict__ mkey,
                                                   unsigned int* __restrict__ mstep) {
#pragma clang fp contract(off)
    const int wgid = blockIdx.x;        // 0..31 ; batch = wgid&7 (keeps a batch's
    const int b = wgid & 7;             // WGs on one XCD under round-robin dispatch
    const int g = wgid >> 3;            // — perf heuristic only, not correctness)
    const int t = threadIdx.x;
    const float* xb = xyz + (size_t)b * N * 3;
    const int n0 = g * PPW + t * PPT;   // this thread's 4 consecutive points

    __shared__ unsigned long long wloc[3];   // rotating local-argmax cells
    __shared__ int wfar;

    f32x2 pxy[4], pzp[2], dd[2];
#pragma unroll
    for (int k = 0; k < 4; ++k) {
        const int n = n0 + k;
        pxy[k].x = xb[n * 3 + 0];
        pxy[k].y = xb[n * 3 + 1];
        pzp[k >> 1][k & 1] = xb[n * 3 + 2];
        dd[k >> 1][k & 1] = 1e10f;
    }
    if (t < 3) wloc[t] = ~0ull;
    if (t == 0)
        __hip_atomic_store(&mstep[wgid], 0u, __ATOMIC_RELEASE, __HIP_MEMORY_SCOPE_AGENT);
    __syncthreads();

    float* nxo = out + OFF_NEWXYZ + (size_t)b * NPOINT * 3;
    int far = 0;
    int cur = 0;

    for (int s = 0; s < NPOINT; ++s) {
        // centroid via uniform scalar loads (global index, any WG can read)
        const int fs = __builtin_amdgcn_readfirstlane(far);
        const float* cp = xb + fs * 3;
        const float cx = cp[0];
        const float cy = cp[1];
        const float cz = cp[2];
        if (g == 0 && t == 0) {
            nxo[s * 3 + 0] = cx;
            nxo[s * 3 + 1] = cy;
            nxo[s * 3 + 2] = cz;
        }
        if (s == NPOINT - 1) break;                  // last argmax is discarded

        const f32x2 cxy = {cx, cy};
        const f32x2 czz = {cz, cz};
#pragma unroll
        for (int j = 0; j < 2; ++j) {                // 2 points per iter, packed
            const f32x2 e0 = pk_sub(pxy[2 * j + 0], cxy);
            const f32x2 e1 = pk_sub(pxy[2 * j + 1], cxy);
            const f32x2 q0 = pk_mul(e0, e0);
            const f32x2 q1 = pk_mul(e1, e1);
            const f32x2 ez = pk_sub(pzp[j], czz);
            const f32x2 z2 = pk_mul(ez, ez);
            f32x2 dist;
            dist.x = (q0.x + q0.y) + z2.x;           // exact left-assoc, no contract
            dist.y = (q1.x + q1.y) + z2.y;
            dd[j] = __builtin_elementwise_min(dd[j], dist);
        }
        // best over the 4 owned points (max exactly associative)
        const f32x2 mp = __builtin_elementwise_max(dd[0], dd[1]);
        const float best = fmaxf(mp.x, mp.y);
        int bk = 3;                                   // smallest k with dd==best
#pragma unroll
        for (int k = 2; k >= 0; --k)
            if (dd[k >> 1][k & 1] == best) bk = k;
        const int bn = n0 + bk;

        // wave max via DPP
        float m = best;
        m = maxdpp<0x111>(m);   // row_shr:1
        m = maxdpp<0x112>(m);   // row_shr:2
        m = maxdpp<0x114>(m);   // row_shr:4
        m = maxdpp<0x118>(m);   // row_shr:8
        m = maxdpp<0x142>(m);   // row_bcast:15
        m = maxdpp<0x143>(m);   // row_bcast:31
        const float wavemax =
            __int_as_float(__builtin_amdgcn_readlane(__float_as_int(m), 63));

        // WG-local argmax: candidate lanes atomic-min packed key into LDS
        if (best == wavemax) {
            const unsigned long long key =
                (((unsigned long long)(~__float_as_uint(best))) << 14) |
                (unsigned long long)(unsigned)bn;
            atomicMin(&wloc[cur], key);
        }
        if (t == 1) wloc[cur == 2 ? 0 : cur + 1] = ~0ull;
        __syncthreads();

        // publish local winner; combine the NW per-WG winners
        if (t == 0) {
            __hip_atomic_store(&mkey[wgid], wloc[cur],
                               __ATOMIC_RELAXED, __HIP_MEMORY_SCOPE_AGENT);
            __hip_atomic_store(&mstep[wgid], (unsigned)(s + 1),
                               __ATOMIC_RELEASE, __HIP_MEMORY_SCOPE_AGENT);
        }
        if (t < NW) {
            const int mb = t * 8 + b;                 // mailbox of WG (g'=t, batch b)
            while (__hip_atomic_load(&mstep[mb], __ATOMIC_ACQUIRE,
                                     __HIP_MEMORY_SCOPE_AGENT) != (unsigned)(s + 1)) {}
            unsigned long long km =
                __hip_atomic_load(&mkey[mb], __ATOMIC_RELAXED, __HIP_MEMORY_SCOPE_AGENT);
            unsigned long long o = __shfl_xor(km, 1);
            if (o < km) km = o;
            o = __shfl_xor(km, 2);
            if (o < km) km = o;
            if (t == 0) wfar = (int)(km & 16383ull);
        }
        __syncthreads();
        far = wfar;
        cur = (cur == 2) ? 0 : cur + 1;
    }
}

// ---------------- Ball query: one 64-lane wave per centroid ----------------
__global__ __launch_bounds__(256) void ballq_kernel(const float* __restrict__ xyz,
                                                    const float* __restrict__ radius_p,
                                                    float* out) {
    const int wib = threadIdx.x >> 6;
    const int lane = threadIdx.x & 63;
    const int gw = blockIdx.x * 4 + wib;   // 0..8191
    const int b = gw >> 10;
    const int s = gw & 1023;

    const float r = radius_p[0];
    const float r2 = __fmul_rn(r, r);

    const float* xb = xyz + (size_t)b * N * 3;
    const float* nx = out + OFF_NEWXYZ + (size_t)(b * NPOINT + s) * 3;
    const float c0 = nx[0], c1 = nx[1], c2 = nx[2];
    const float ss_s = __fadd_rn(__fadd_rn(__fmul_rn(c0, c0), __fmul_rn(c1, c1)),
                                 __fmul_rn(c2, c2));

    float* oidx = out + OFF_IDX + (size_t)(b * NPOINT + s) * NSAMPLE;
    float* ogx  = out + OFF_GXYZ + (size_t)(b * NPOINT + s) * NSAMPLE * 3;

    int filled = 0;
    int first = -1;
    for (int n0 = 0; n0 < N; n0 += 64) {
        const int n = n0 + lane;
        const float x = xb[n * 3 + 0];
        const float y = xb[n * 3 + 1];
        const float z = xb[n * 3 + 2];
        const float ssx = __fadd_rn(__fadd_rn(__fmul_rn(x, x), __fmul_rn(y, y)),
                                    __fmul_rn(z, z));
        const float dot = __fadd_rn(__fadd_rn(__fmul_rn(c0, x), __fmul_rn(c1, y)),
                                    __fmul_rn(c2, z));
        const float d2 = __fsub_rn(__fadd_rn(ss_s, ssx), __fmul_rn(2.0f, dot));
        const bool in = d2 < r2;
        const unsigned long long m = __ballot(in);
        if (first < 0 && m != 0ull) first = n0 + (int)__builtin_ctzll(m);
        if (in) {
            const int pos = filled + (int)__popcll(m & ((1ull << lane) - 1ull));
            if (pos < NSAMPLE) {
                oidx[pos] = (float)n;
                ogx[pos * 3 + 0] = __fsub_rn(x, c0);
                ogx[pos * 3 + 1] = __fsub_rn(y, c1);
                ogx[pos * 3 + 2] = __fsub_rn(z, c2);
            }
        }
        filled += (int)__popcll(m);
        if (filled >= NSAMPLE) break;
    }
    if (filled < NSAMPLE) {
        if (first < 0) first = 0;
        const float fx = xb[first * 3 + 0];
        const float fy = xb[first * 3 + 1];
        const float fz = xb[first * 3 + 2];
        const float g0 = __fsub_rn(fx, c0);
        const float g1 = __fsub_rn(fy, c1);
        const float g2 = __fsub_rn(fz, c2);
        for (int pos = filled + lane; pos < NSAMPLE; pos += 64) {
            oidx[pos] = (float)first;
            ogx[pos * 3 + 0] = g0;
            ogx[pos * 3 + 1] = g1;
            ogx[pos * 3 + 2] = g2;
        }
    }
}

// ---------------- new_points gather: one block per (b,s) ----------------
__global__ __launch_bounds__(256) void gather_kernel(const float* __restrict__ points,
                                                     float* out) {
    const int blk = blockIdx.x;            // b*NPOINT + s
    const int w = threadIdx.x >> 6;
    const int lane = threadIdx.x & 63;
    const int b = blk >> 10;

    const float* oidx = out + OFF_IDX + (size_t)blk * NSAMPLE;
    const float* pb = points + (size_t)b * N * CDIM;
    float* onp = out + OFF_NEWPTS + (size_t)blk * NSAMPLE * CDIM;

#pragma unroll
    for (int i = 0; i < 8; ++i) {
        const int slot = w * 8 + i;
        const int n = (int)oidx[slot];
        const float2 v = *(const float2*)(pb + (size_t)n * CDIM + lane * 2);
        *(float2*)(onp + (size_t)slot * CDIM + lane * 2) = v;
    }
}

extern "C" void kernel_launch(void* const* d_in, const int* in_sizes, int n_in,
                              void* d_out, int out_size, void* d_ws, size_t ws_size,
                              hipStream_t stream) {
    // inputs: [0]=npoint(int,1), [1]=radius(f32,1), [2]=xyz(f32, B*N*3), [3]=points(f32, B*N*CDIM)
    const float* xyz = (const float*)d_in[2];
    const float* points = (const float*)d_in[3];
    const float* radius = (const float*)d_in[1];
    float* out = (float*)d_out;

    unsigned long long* mkey = (unsigned long long*)d_ws;            // 32 * 8 B
    unsigned int* mstep = (unsigned int*)((char*)d_ws + 256);        // 32 * 4 B

    hipLaunchKernelGGL(fps_kernel, dim3(B * NW), dim3(1024), 0, stream, xyz, out, mkey, mstep);
    hipLaunchKernelGGL(ballq_kernel, dim3((B * NPOINT) / 4), dim3(256), 0, stream, xyz, radius, out);
    hipLaunchKernelGGL(gather_kernel, dim3(B * NPOINT), dim3(256), 0, stream, points, out);
}

// Round 16
// 1548.936 us; speedup vs baseline: 1.7545x; 1.7545x over previous
//
#include <hip/hip_runtime.h>

#define B 8
#define N 16384
#define NPOINT 1024
#define NSAMPLE 32
#define CDIM 128
#define CELLS 4096

// d_out layout (floats), reference return order:
// new_xyz [B,NPOINT,3], new_points [B,NPOINT,NSAMPLE,CDIM], idx [B,NPOINT,NSAMPLE], grouped_xyz [B,NPOINT,NSAMPLE,3]
#define OFF_NEWXYZ 0
#define OFF_NEWPTS (B * NPOINT * 3)                           // 24576
#define OFF_IDX    (OFF_NEWPTS + B * NPOINT * NSAMPLE * CDIM) // 33579008
#define OFF_GXYZ   (OFF_IDX + B * NPOINT * NSAMPLE)           // 33841152

typedef unsigned long long u64;

// u64-min DPP step: candidate = lane-shifted key (both halves move coherently);
// invalid lanes keep old (=own) -> identity for min.
template <int CTRL>
__device__ __forceinline__ u64 mindpp_u64(u64 k) {
    const int lo = (int)(unsigned)(k & 0xffffffffull);
    const int hi = (int)(unsigned)(k >> 32);
    const int lo2 = __builtin_amdgcn_update_dpp(lo, lo, CTRL, 0xf, 0xf, false);
    const int hi2 = __builtin_amdgcn_update_dpp(hi, hi, CTRL, 0xf, 0xf, false);
    const u64 kt = ((u64)(unsigned)hi2 << 32) | (unsigned)lo2;
    return kt < k ? kt : k;
}

__device__ __forceinline__ int spread3(int v) {   // 4-bit -> bits 0,3,6,9
    return (v & 1) | ((v & 2) << 2) | ((v & 4) << 4) | ((v & 8) << 6);
}

// ---------- sort: Morton-bin each batch into AoS (x,y,z,(float)n) ----------
// One block per batch. Intra-cell order is nondeterministic (atomicAdd), but
// all downstream reductions are (max d, min orig-n) exact -> outputs are
// bitwise independent of storage order.
__global__ __launch_bounds__(1024) void sort_kernel(const float* __restrict__ xyz,
                                                    float* __restrict__ sorted) {
    const int b = blockIdx.x;
    const int t = threadIdx.x;
    const float* xb = xyz + (size_t)b * N * 3;

    __shared__ unsigned int hist[CELLS];     // 16 KiB
    __shared__ unsigned int waveS[16];

#pragma unroll
    for (int i = 0; i < CELLS / 1024; ++i) hist[i * 1024 + t] = 0;
    __syncthreads();

    int cell[16];
#pragma unroll
    for (int k = 0; k < 16; ++k) {
        const int n = k * 1024 + t;
        const float x = xb[n * 3 + 0];
        const float y = xb[n * 3 + 1];
        const float z = xb[n * 3 + 2];
        int cx = (int)(x * 16.0f); cx = cx < 0 ? 0 : (cx > 15 ? 15 : cx);
        int cy = (int)(y * 16.0f); cy = cy < 0 ? 0 : (cy > 15 ? 15 : cy);
        int cz = (int)(z * 16.0f); cz = cz < 0 ? 0 : (cz > 15 ? 15 : cz);
        cell[k] = spread3(cx) | (spread3(cy) << 1) | (spread3(cz) << 2);
        atomicAdd(&hist[cell[k]], 1u);
    }
    __syncthreads();

    // exclusive scan of hist[4096]: thread owns 4 consecutive cells
    const unsigned h0 = hist[4 * t + 0], h1 = hist[4 * t + 1],
                   h2 = hist[4 * t + 2], h3 = hist[4 * t + 3];
    const unsigned sum4 = h0 + h1 + h2 + h3;
    const int wid = t >> 6, lane = t & 63;
    unsigned inc = sum4;                                  // wave inclusive scan
#pragma unroll
    for (int off = 1; off < 64; off <<= 1) {
        const unsigned v = __shfl_up(inc, off);
        if (lane >= off) inc += v;
    }
    if (lane == 63) waveS[wid] = inc;
    __syncthreads();
    unsigned wbase = 0;
    {
        unsigned ws = (lane < 16) ? waveS[lane] : 0u;     // scan 16 wave sums
        unsigned wi = ws;
#pragma unroll
        for (int off = 1; off < 16; off <<= 1) {
            const unsigned v = __shfl_up(wi, off);
            if (lane >= off) wi += v;
        }
        wbase = __shfl(wi - ws, wid);                     // exclusive base of my wave
    }
    const unsigned base = wbase + (inc - sum4);           // exclusive base of my 4 cells
    __syncthreads();                                      // all reads of hist done
    hist[4 * t + 0] = base;
    hist[4 * t + 1] = base + h0;
    hist[4 * t + 2] = base + h0 + h1;
    hist[4 * t + 3] = base + h0 + h1 + h2;
    __syncthreads();

    float4* sb = (float4*)sorted + (size_t)b * N;
#pragma unroll
    for (int k = 0; k < 16; ++k) {
        const int n = k * 1024 + t;
        const float x = xb[n * 3 + 0];
        const float y = xb[n * 3 + 1];
        const float z = xb[n * 3 + 2];
        const unsigned pos = atomicAdd(&hist[cell[k]], 1u);
        sb[pos] = make_float4(x, y, z, (float)n);
    }
}

// ---------------- FPS: one block (1024 threads) per batch ----------------
// Exact f32 left-assoc distance; argmax = (max d, first/min index) carried
// exactly via (mval, mn) pairs and u64 keys. Thread owns 16 Morton-adjacent
// points; registers hold only d[16] + bbox[6] + cached (mval,mn) -> no spill.
// Per step: bbox test (conservative 1.0001 margin; fp err ~3e-7) decides if
// the thread's d can change; only executing waves re-stream their 16 points
// from L2. Skipped threads' cached (mval,mn) remain exact.
__global__ __launch_bounds__(1024) void fps_kernel(const float* __restrict__ xyz,
                                                   const float* __restrict__ sorted,
                                                   float* out) {
#pragma clang fp contract(off)
    const int b = blockIdx.x;
    const int t = threadIdx.x;
    const float* xb = xyz + (size_t)b * N * 3;
    const float4* sb = (const float4*)sorted + (size_t)b * N;

    __shared__ u64 swkey[2][16];
    const int wid = t >> 6;
    const int lane = t & 63;

    float d[16];
    float lox = 1e30f, hix = -1e30f, loy = 1e30f, hiy = -1e30f, loz = 1e30f, hiz = -1e30f;
#pragma unroll
    for (int k = 0; k < 16; ++k) {
        const float4 v = sb[t * 16 + k];
        lox = fminf(lox, v.x); hix = fmaxf(hix, v.x);
        loy = fminf(loy, v.y); hiy = fmaxf(hiy, v.y);
        loz = fminf(loz, v.z); hiz = fmaxf(hiz, v.z);
        d[k] = 1e10f;
    }
    float mval = 1e10f;       // cached max_k d[k]
    int   mn   = 0;           // cached min orig-n among argmax
    __syncthreads();

    float* nxo = out + OFF_NEWXYZ + (size_t)b * NPOINT * 3;
    int far = 0;

    for (int s = 0; s < NPOINT; ++s) {
        const int fs = __builtin_amdgcn_readfirstlane(far);
        const float cx = xb[fs * 3 + 0];
        const float cy = xb[fs * 3 + 1];
        const float cz = xb[fs * 3 + 2];
        if (t == 0) {
            nxo[s * 3 + 0] = cx;
            nxo[s * 3 + 1] = cy;
            nxo[s * 3 + 2] = cz;
        }
        if (s == NPOINT - 1) break;                  // last argmax is discarded

        // conservative bbox-distance skip test
        const float ax = fmaxf(fmaxf(__fsub_rn(lox, cx), __fsub_rn(cx, hix)), 0.0f);
        const float ay = fmaxf(fmaxf(__fsub_rn(loy, cy), __fsub_rn(cy, hiy)), 0.0f);
        const float az = fmaxf(fmaxf(__fsub_rn(loz, cz), __fsub_rn(cz, hiz)), 0.0f);
        const float md2 = __fadd_rn(__fadd_rn(__fmul_rn(ax, ax), __fmul_rn(ay, ay)),
                                    __fmul_rn(az, az));
        const bool ex = !(md2 > __fmul_rn(mval, 1.0001f));
        if (__ballot(ex) != 0ull) {
            if (ex) {
                float bv = -1.0f;
                int bn2 = 0x7fffffff;
#pragma unroll
                for (int k = 0; k < 16; ++k) {
                    const float4 v = sb[t * 16 + k];
                    const float dx = __fsub_rn(v.x, cx);
                    const float dy = __fsub_rn(v.y, cy);
                    const float dz = __fsub_rn(v.z, cz);
                    const float dist = __fadd_rn(
                        __fadd_rn(__fmul_rn(dx, dx), __fmul_rn(dy, dy)),
                        __fmul_rn(dz, dz));
                    const float dk = fminf(d[k], dist);
                    d[k] = dk;
                    const int nk = (int)v.w;
                    if (dk > bv) { bv = dk; bn2 = nk; }
                    else if (dk == bv && nk < bn2) { bn2 = nk; }
                }
                mval = bv;
                mn = bn2;
            }
        }
        // wave reduce: u64 key = (~bits(maxd) << 14) | n ; u64-min == (max d, min n)
        u64 key = ((u64)(unsigned)(~__float_as_uint(mval)) << 14) | (unsigned)mn;
        key = mindpp_u64<0x111>(key);   // row_shr:1
        key = mindpp_u64<0x112>(key);   // row_shr:2
        key = mindpp_u64<0x114>(key);   // row_shr:4
        key = mindpp_u64<0x118>(key);   // row_shr:8
        key = mindpp_u64<0x142>(key);   // row_bcast:15
        key = mindpp_u64<0x143>(key);   // row_bcast:31  -> lane 63 = wave min
        if (lane == 63) swkey[s & 1][wid] = key;
        __syncthreads();
        // block reduce: every lane reads slot (lane&15); 4 in-row DPP levels
        // put the min of all 16 slots in lane 15 of each row
        u64 kk = swkey[s & 1][lane & 15];
        kk = mindpp_u64<0x111>(kk);
        kk = mindpp_u64<0x112>(kk);
        kk = mindpp_u64<0x114>(kk);
        kk = mindpp_u64<0x118>(kk);
        const int lo15 = __builtin_amdgcn_readlane((int)(unsigned)(kk & 0xffffffffull), 15);
        far = lo15 & 16383;
    }
}

// ---------------- Ball query: one 64-lane wave per centroid ----------------
// Selects the 32 smallest indices n with d2 < r^2 where
// d2 = (|s|^2 + |x|^2) - 2*(s.x)  (left-assoc f32, matching the reference).
__global__ __launch_bounds__(256) void ballq_kernel(const float* __restrict__ xyz,
                                                    const float* __restrict__ radius_p,
                                                    float* out) {
    const int wib = threadIdx.x >> 6;
    const int lane = threadIdx.x & 63;
    const int gw = blockIdx.x * 4 + wib;   // 0..8191
    const int b = gw >> 10;
    const int s = gw & 1023;

    const float r = radius_p[0];
    const float r2 = __fmul_rn(r, r);

    const float* xb = xyz + (size_t)b * N * 3;
    const float* nx = out + OFF_NEWXYZ + (size_t)(b * NPOINT + s) * 3;
    const float c0 = nx[0], c1 = nx[1], c2 = nx[2];
    const float ss_s = __fadd_rn(__fadd_rn(__fmul_rn(c0, c0), __fmul_rn(c1, c1)),
                                 __fmul_rn(c2, c2));

    float* oidx = out + OFF_IDX + (size_t)(b * NPOINT + s) * NSAMPLE;
    float* ogx  = out + OFF_GXYZ + (size_t)(b * NPOINT + s) * NSAMPLE * 3;

    int filled = 0;
    int first = -1;
    for (int n0 = 0; n0 < N; n0 += 64) {
        const int n = n0 + lane;
        const float x = xb[n * 3 + 0];
        const float y = xb[n * 3 + 1];
        const float z = xb[n * 3 + 2];
        const float ssx = __fadd_rn(__fadd_rn(__fmul_rn(x, x), __fmul_rn(y, y)),
                                    __fmul_rn(z, z));
        const float dot = __fadd_rn(__fadd_rn(__fmul_rn(c0, x), __fmul_rn(c1, y)),
                                    __fmul_rn(c2, z));
        const float d2 = __fsub_rn(__fadd_rn(ss_s, ssx), __fmul_rn(2.0f, dot));
        const bool in = d2 < r2;
        const unsigned long long m = __ballot(in);
        if (first < 0 && m != 0ull) first = n0 + (int)__builtin_ctzll(m);
        if (in) {
            const int pos = filled + (int)__popcll(m & ((1ull << lane) - 1ull));
            if (pos < NSAMPLE) {
                oidx[pos] = (float)n;
                ogx[pos * 3 + 0] = __fsub_rn(x, c0);
                ogx[pos * 3 + 1] = __fsub_rn(y, c1);
                ogx[pos * 3 + 2] = __fsub_rn(z, c2);
            }
        }
        filled += (int)__popcll(m);
        if (filled >= NSAMPLE) break;
    }
    if (filled < NSAMPLE) {
        if (first < 0) first = 0;
        const float fx = xb[first * 3 + 0];
        const float fy = xb[first * 3 + 1];
        const float fz = xb[first * 3 + 2];
        const float g0 = __fsub_rn(fx, c0);
        const float g1 = __fsub_rn(fy, c1);
        const float g2 = __fsub_rn(fz, c2);
        for (int pos = filled + lane; pos < NSAMPLE; pos += 64) {
            oidx[pos] = (float)first;
            ogx[pos * 3 + 0] = g0;
            ogx[pos * 3 + 1] = g1;
            ogx[pos * 3 + 2] = g2;
        }
    }
}

// ---------------- new_points gather: one block per (b,s) ----------------
__global__ __launch_bounds__(256) void gather_kernel(const float* __restrict__ points,
                                                     float* out) {
    const int blk = blockIdx.x;            // b*NPOINT + s
    const int w = threadIdx.x >> 6;
    const int lane = threadIdx.x & 63;
    const int b = blk >> 10;

    const float* oidx = out + OFF_IDX + (size_t)blk * NSAMPLE;
    const float* pb = points + (size_t)b * N * CDIM;
    float* onp = out + OFF_NEWPTS + (size_t)blk * NSAMPLE * CDIM;

#pragma unroll
    for (int i = 0; i < 8; ++i) {
        const int slot = w * 8 + i;
        const int n = (int)oidx[slot];
        const float2 v = *(const float2*)(pb + (size_t)n * CDIM + lane * 2);
        *(float2*)(onp + (size_t)slot * CDIM + lane * 2) = v;
    }
}

extern "C" void kernel_launch(void* const* d_in, const int* in_sizes, int n_in,
                              void* d_out, int out_size, void* d_ws, size_t ws_size,
                              hipStream_t stream) {
    // inputs: [0]=npoint(int,1), [1]=radius(f32,1), [2]=xyz(f32, B*N*3), [3]=points(f32, B*N*CDIM)
    const float* xyz = (const float*)d_in[2];
    const float* points = (const float*)d_in[3];
    const float* radius = (const float*)d_in[1];
    float* out = (float*)d_out;

    // sorted AoS scratch lives in the new_points output region (2 MB used of
    // 134 MB); gather_kernel fully overwrites it afterwards.
    float* sorted = out + OFF_NEWPTS;

    hipLaunchKernelGGL(sort_kernel, dim3(B), dim3(1024), 0, stream, xyz, sorted);
    hipLaunchKernelGGL(fps_kernel, dim3(B), dim3(1024), 0, stream, xyz, sorted, out);
    hipLaunchKernelGGL(ballq_kernel, dim3((B * NPOINT) / 4), dim3(256), 0, stream, xyz, radius, out);
    hipLaunchKernelGGL(gather_kernel, dim3(B * NPOINT), dim3(256), 0, stream, points, out);
}